// Round 3
// baseline (284.724 us; speedup 1.0000x reference)
//
#include <hip/hip_runtime.h>

#define B 64
#define N 1024
#define E 16384
#define WPR 32          // words per adjacency row = N/32
#define NITER 5

// ---- workspace layout (bytes) ----
// [ Kmax 256B | feats 256KiB ]  <- zeroed by memset (tiny)
// [ adj 8MiB | lab 256KiB | gram 16KiB ] <- fully overwritten every call
#define K_OFF     0
#define K_BYTES   ((size_t)256)
#define FEATS_OFF (K_OFF + K_BYTES)
#define FEATS_BYTES ((size_t)B * N * 4)
#define ZERO_BYTES (FEATS_OFF + FEATS_BYTES)
#define ADJ_OFF   (ZERO_BYTES)
#define ADJ_BYTES ((size_t)B * N * WPR * 4)
#define LAB_OFF   (ADJ_OFF + ADJ_BYTES)
#define LAB_BYTES ((size_t)B * N * 4)
#define GRAM_OFF  (LAB_OFF + LAB_BYTES)
#define GRAM_BYTES ((size_t)B * B * 4)

// Bit adjacency built in LDS: 4 blocks per graph, each owns 256 rows (32 KiB).
// Every block scans all E edges of its graph, sets bits with LDS atomicOr
// (idempotent -> duplicate edges collapse like .set(True)), writes its rows
// out coalesced, and fuses the per-graph max-degree (Kmax) reduction.
// R2 evidence: global-atomicOr build was 42us with 33MB write traffic.
__global__ void __launch_bounds__(256) build_adj_k(const int* __restrict__ src,
                                                   const int* __restrict__ dst,
                                                   unsigned int* __restrict__ adj,
                                                   int* __restrict__ Kmax) {
    __shared__ unsigned int s_adj[256 * WPR];   // 32 KiB: rows [row_base, row_base+256)
    __shared__ int red[256];
    int t = threadIdx.x;
    int b = blockIdx.x >> 2;
    int part = blockIdx.x & 3;
    int row_base = part << 8;

    // zero LDS tile
    uint4* s4 = (uint4*)s_adj;
#pragma unroll
    for (int k = 0; k < 8; ++k) s4[t + k * 256] = make_uint4(0, 0, 0, 0);
    __syncthreads();

    // scan this graph's edges, keep those whose src row lands in our tile
    const int* sg = src + (size_t)b * E;
    const int* dg = dst + (size_t)b * E;
    for (int e = t; e < E; e += 256) {
        int s = sg[e];
        int r = s - row_base;
        if ((unsigned)r < 256u) {
            int d = dg[e];
            atomicOr(&s_adj[r * WPR + (d >> 5)], 1u << (d & 31));
        }
    }
    __syncthreads();

    // coalesced write-out (LDS layout == global layout for these rows)
    uint4* g4 = (uint4*)(adj + ((size_t)b * N + row_base) * WPR);
#pragma unroll
    for (int k = 0; k < 8; ++k) g4[t + k * 256] = s4[t + k * 256];

    // fused Kmax: popcount own row, block max-reduce, 4 atomics/graph
    const uint4* row = (const uint4*)(s_adj + t * WPR);
    int d = 0;
#pragma unroll
    for (int w = 0; w < WPR / 4; ++w) {
        uint4 v = row[w];
        d += __popc(v.x) + __popc(v.y) + __popc(v.z) + __popc(v.w);
    }
    red[t] = d;
    __syncthreads();
#pragma unroll
    for (int off = 128; off > 0; off >>= 1) {
        if (t < off) red[t] = max(red[t], red[t + off]);
        __syncthreads();
    }
    if (t == 0) atomicMax(&Kmax[b], red[0]);
}

// labels_cur = initial labels; bincount (labels < 16) via LDS aggregation.
__global__ void init_k(const int* __restrict__ lab_in, int* __restrict__ lab,
                       unsigned int* __restrict__ feats) {
    __shared__ unsigned int cnt[16];
    int t = threadIdx.x;
    if (t < 16) cnt[t] = 0;
    __syncthreads();
    int idx = blockIdx.x * 256 + t;                 // block lies in one graph
    int l = lab_in[idx];
    lab[idx] = l;
    atomicAdd(&cnt[l], 1u);
    __syncthreads();
    if (t < 16) atomicAdd(&feats[(size_t)(blockIdx.x >> 2) * N + t], cnt[t]);
}

// One fused WL iteration, one graph per block. Unique-inverse WITHOUT sorting:
//   hash -> order-isomorphic uint key (sign-flip; -0 canonicalized to +0),
//   c_i = #{j : key_j < key_i}   (broadcast LDS counting loop),
//   distinct value classes have distinct start offsets c -> flag[c]=1,
//   inclusive scan -> rank_i = scan[c_i]-1.
// Replaces R2's 55-stage bitonic sort (~25us of barriered LDS traffic).
__global__ void __launch_bounds__(1024) wl_iter_k(const unsigned int* __restrict__ adj,
                                                  const int* __restrict__ Kmax,
                                                  const float* __restrict__ hw,
                                                  int* __restrict__ lab,
                                                  unsigned int* __restrict__ feats) {
    __shared__ unsigned int s_key[N];
    __shared__ int s_scan[N];
    __shared__ int s_lab[N];            // labels, later reused as rank counts
    int b = blockIdx.x;
    int t = threadIdx.x;
    s_lab[t] = lab[(size_t)b * N + t];
    __syncthreads();

    // deg + seg from this node's adjacency row (L2-resident)
    const unsigned int* row = adj + ((size_t)b * N + t) * WPR;
    int s = 0, d = 0;
#pragma unroll 4
    for (int w = 0; w < WPR; ++w) {
        unsigned int word = row[w];
        d += __popc(word);
        int base = w << 5;
        while (word) {
            int j = __ffs(word) - 1;
            word &= word - 1;
            s += s_lab[base + j];
        }
    }
    // hash with exact _rn op order -> bitwise match vs numpy reference
    float Kf   = (float)Kmax[b];
    float labf = (float)s_lab[t];
    float degf = (float)d;
    float segf = (float)s;              // exact: |seg| < 2^24
    float w0 = hw[0], w1 = hw[1];
    float t1 = __fmul_rn(__fmul_rn(Kf, w0), labf);
    float t2 = __fmul_rn(w1, __fsub_rn(__fadd_rn(segf, degf), Kf));
    float h  = __fadd_rn(t1, t2);
    // monotone float->uint (equal floats <-> equal keys; -0 == +0 preserved)
    unsigned int bits = __float_as_uint(h);
    if (bits == 0x80000000u) bits = 0u;
    unsigned int ikey = (bits & 0x80000000u) ? ~bits : (bits | 0x80000000u);
    s_key[t] = ikey;
    __syncthreads();

    // c_i = #{j : key_j < ikey}; uniform-address (broadcast) uint4 LDS reads
    int c = 0;
    const uint4* k4 = (const uint4*)s_key;
#pragma unroll 4
    for (int j = 0; j < N / 4; ++j) {
        uint4 v = k4[j];
        c += (v.x < ikey) + (v.y < ikey) + (v.z < ikey) + (v.w < ikey);
    }

    // class-start flags + inclusive scan -> dense rank
    s_scan[t] = 0;
    __syncthreads();
    s_scan[c] = 1;                      // same class -> same c; benign same-value race
    __syncthreads();
    for (int off = 1; off < N; off <<= 1) {
        int v = (t >= off) ? s_scan[t - off] : 0;
        __syncthreads();
        s_scan[t] += v;
        __syncthreads();
    }
    int rank = s_scan[c] - 1;
    lab[(size_t)b * N + t] = rank;

    // bincount ranks: LDS aggregate, then plain global read-modify-write
    s_lab[t] = 0;
    __syncthreads();
    atomicAdd((unsigned int*)&s_lab[rank], 1u);
    __syncthreads();
    unsigned int cnt = (unsigned int)s_lab[t];
    if (cnt) feats[(size_t)b * N + t] += cnt;
}

// gram[i,j] = dot(feats[i], feats[j]) — exact in int32
__global__ void gram_k(const unsigned int* __restrict__ feats, float* __restrict__ gram) {
    int i = blockIdx.x, j = blockIdx.y;
    int lane = threadIdx.x;               // 64 lanes = one wave
    const unsigned int* fi = feats + (size_t)i * N;
    const unsigned int* fj = feats + (size_t)j * N;
    int s = 0;
    for (int l = lane; l < N; l += 64) s += (int)(fi[l] * fj[l]);
#pragma unroll
    for (int off = 32; off > 0; off >>= 1) s += __shfl_down(s, off);
    if (lane == 0) gram[i * B + j] = (float)s;
}

__global__ void norm_k(const float* __restrict__ gram, float* __restrict__ out) {
    int idx = blockIdx.x * blockDim.x + threadIdx.x;
    if (idx >= B * B) return;
    int i = idx >> 6, j = idx & 63;
    out[idx] = gram[idx] / sqrtf(gram[i * B + i] * gram[j * B + j]);
}

extern "C" void kernel_launch(void* const* d_in, const int* in_sizes, int n_in,
                              void* d_out, int out_size, void* d_ws, size_t ws_size,
                              hipStream_t stream) {
    const int*   esrc = (const int*)d_in[0];
    const int*   edst = (const int*)d_in[1];
    const int*   lab0 = (const int*)d_in[2];
    const float* hw   = (const float*)d_in[3];

    char* ws = (char*)d_ws;
    int*          Kmax  = (int*)(ws + K_OFF);
    unsigned int* feats = (unsigned int*)(ws + FEATS_OFF);
    unsigned int* adj   = (unsigned int*)(ws + ADJ_OFF);
    int*          lab   = (int*)(ws + LAB_OFF);
    float*        gram  = (float*)(ws + GRAM_OFF);

    hipMemsetAsync(d_ws, 0, ZERO_BYTES, stream);    // Kmax + feats only

    build_adj_k<<<B * 4, 256, 0, stream>>>(esrc, edst, adj, Kmax);
    init_k<<<B * N / 256, 256, 0, stream>>>(lab0, lab, feats);

    for (int it = 0; it < NITER; ++it)
        wl_iter_k<<<B, 1024, 0, stream>>>(adj, Kmax, hw, lab, feats);

    gram_k<<<dim3(B, B), 64, 0, stream>>>(feats, gram);
    norm_k<<<(B * B + 255) / 256, 256, 0, stream>>>(gram, (float*)d_out);
}